// Round 4
// baseline (76.926 us; speedup 1.0000x reference)
//
#include <hip/hip_runtime.h>

// Problem constants: B=32, L1=L2=64, DIM_HID=256, FEAT=512
#define BB 32
#define LL 64
#define HH 256
#define FF 512
#define WSTRIDE 1024   // W is [256, 1024] row-major
#define HT 16          // h-tile per block: 512 blocks = 2/CU
#define BK 64          // K-tile in fp32 (8 steps over K=512)
#define NKT (FF / BK)
#define YSTR 17        // f32 y-tile stride (16 + 1 pad)

// LDS byte layout per buffer (fp32 tiles, linear rows of 64 floats = 256 B)
#define A1OFF 0        // 64 x 64 f32 = 16384 B
#define A2OFF 16384
#define W1OFF 32768    // 16 x 64 f32 = 4096 B
#define W2OFF 36864
#define BUFB  40960    // bytes per buffer; x2 buffers = 81920 B -> 2 blocks/CU

typedef float float4v __attribute__((ext_vector_type(4)));
typedef short short8  __attribute__((ext_vector_type(8)));

// Packed fp32x2 -> bf16x2 (RNE in HW). No builtin on gfx950 -> inline asm.
static __device__ __forceinline__ unsigned int cvt_pk_bf16(float lo, float hi) {
    unsigned int r;
    asm("v_cvt_pk_bf16_f32 %0, %1, %2" : "=v"(r) : "v"(lo), "v"(hi));
    return r;
}

// 8 fp32 (two float4) -> short8 bf16
static __device__ __forceinline__ short8 cvt8(float4 lo, float4 hi) {
    union { short8 s; unsigned int u[4]; } o;
    o.u[0] = cvt_pk_bf16(lo.x, lo.y);
    o.u[1] = cvt_pk_bf16(lo.z, lo.w);
    o.u[2] = cvt_pk_bf16(hi.x, hi.y);
    o.u[3] = cvt_pk_bf16(hi.z, hi.w);
    return o.s;
}

// Async global -> LDS, 16 B/lane. LDS dest = wave-uniform base + lane*16.
static __device__ __forceinline__ void gl16(const float* g, void* l) {
    __builtin_amdgcn_global_load_lds(
        (const __attribute__((address_space(1))) void*)(const void*)g,
        (__attribute__((address_space(3))) void*)l, 16, 0, 0);
}

// ---------------- Single fused kernel ----------------
// One block per (batch b, h-tile of 16). 512 blocks = 2/CU (80 KB LDS each).
// fp32 tiles staged via global_load_lds (double-buffered, ONE barrier/K-step);
// bank-conflict swizzle applied on the PER-LANE GLOBAL ADDRESS (granule index
// ^= row&7, 16B granules) so LDS dest stays linear; fragment reads XOR the
// same mask. fp32 -> bf16 conversion happens at fragment read (v_cvt_pk).
__global__ __launch_bounds__(256)
void fused_kernel(const float* __restrict__ x1,
                  const float* __restrict__ x2,
                  const float* __restrict__ W,
                  const int* __restrict__ s1p,
                  const int* __restrict__ s2p,
                  const float* __restrict__ bias,
                  float* __restrict__ out) {
    const int b  = blockIdx.x;
    const int h0 = blockIdx.y * HT;

    __shared__ __align__(16) unsigned char smem[2 * BUFB];   // 81920 B
    // epilogue overlay on buffer 0 (dead after the final barrier)
    float (*y1t)[YSTR]     = (float (*)[YSTR])(smem);
    float (*y2t)[YSTR]     = (float (*)[YSTR])(smem + 4352);
    float (*partial)[YSTR] = (float (*)[YSTR])(smem + 8704);

    const int t      = threadIdx.x;
    const int lane   = t & 63;
    const int wid    = t >> 6;          // 0..3
    const int srcSel = wid >> 1;        // 0: y1, 1: y2
    const int mrow   = (wid & 1) * 32;  // wave's 32-row half
    const int lm     = lane & 15;
    const int quad   = lane >> 4;

    // staging map: thread covers (row = srow [+16q for A], granule slot t&15).
    // Global granule = slot ^ (row&7); row&7 == srow&7 for all q (q*16 ≡ 0 mod 8).
    const int srow = t >> 4;                       // 0..15
    const int sg   = (t & 15) ^ (srow & 7);        // swizzled source granule

    const float* a1g = x1 + (size_t)(b * LL + srow) * FF + sg * 4;
    const float* a2g = x2 + (size_t)(b * LL + srow) * FF + sg * 4;
    const float* w1g = W + (size_t)(h0 + srow) * WSTRIDE + sg * 4;
    const float* w2g = w1g + FF;

    float4v acc[2];
    acc[0] = (float4v){0.f, 0.f, 0.f, 0.f};
    acc[1] = (float4v){0.f, 0.f, 0.f, 0.f};

    // fragment read offsets. Logical granule g stored at slot g^(row&7);
    // A-fragment k-local = ks*32 + quad*8 floats -> granules ks*8 + quad*2, +1.
    // XOR mask m = lm&7 (rows mrow+lm, +16, and B-row lm all share row&7 = m).
    // ks*8 granule step survives the XOR (bit 3 untouched) -> +128 B.
    const int m     = lm & 7;
    const int offLo = (((quad * 2)     ^ m) * 16);   // bytes within row
    const int offHi = (((quad * 2 + 1) ^ m) * 16);
    const int aRowOff = (srcSel ? A2OFF : A1OFF) + (mrow + lm) * 256;
    const int bRowOff = (srcSel ? W2OFF : W1OFF) + lm * 256;

    // issue one K-tile's staging (10 global_load_lds per thread)
    auto issue = [&](int kt, int bsel) {
        unsigned char* Lb = smem + bsel * BUFB;
        const int ko = kt * BK;
        #pragma unroll
        for (int q = 0; q < 4; ++q) {
            gl16(a1g + ko + (size_t)q * (16 * FF), Lb + A1OFF + q * 4096 + wid * 1024);
            gl16(a2g + ko + (size_t)q * (16 * FF), Lb + A2OFF + q * 4096 + wid * 1024);
        }
        gl16(w1g + ko, Lb + W1OFF + wid * 1024);
        gl16(w2g + ko, Lb + W2OFF + wid * 1024);
    };

    issue(0, 0);
    __syncthreads();   // vmcnt(0): tile 0 resident

    for (int kt = 0; kt < NKT; ++kt) {
        if (kt + 1 < NKT) issue(kt + 1, (kt + 1) & 1);  // flies during MFMA phase

        const unsigned char* Lb  = smem + (kt & 1) * BUFB;
        const unsigned char* pA0 = Lb + aRowOff;
        const unsigned char* pA1 = pA0 + 16 * 256;
        const unsigned char* pB  = Lb + bRowOff;

        #pragma unroll
        for (int ks = 0; ks < 2; ++ks) {
            const int kb = ks * 128;
            const float4 a0lo = *(const float4*)(pA0 + kb + offLo);
            const float4 a0hi = *(const float4*)(pA0 + kb + offHi);
            const float4 a1lo = *(const float4*)(pA1 + kb + offLo);
            const float4 a1hi = *(const float4*)(pA1 + kb + offHi);
            const float4 blo  = *(const float4*)(pB  + kb + offLo);
            const float4 bhi  = *(const float4*)(pB  + kb + offHi);
            const short8 a0 = cvt8(a0lo, a0hi);
            const short8 a1 = cvt8(a1lo, a1hi);
            const short8 b0 = cvt8(blo, bhi);
            acc[0] = __builtin_amdgcn_mfma_f32_16x16x32_bf16(a0, b0, acc[0], 0, 0, 0);
            acc[1] = __builtin_amdgcn_mfma_f32_16x16x32_bf16(a1, b0, acc[1], 0, 0, 0);
        }
        __syncthreads();  // drains lgkm (reads done) + vm (tile kt+1 resident)
    }

    // epilogue -> LDS y-tiles (overlay); fold bias into y2'
    // C/D layout: col = lane&15, row = quad*4 + j (m89-verified)
    {
        float (*yt)[YSTR] = srcSel ? y2t : y1t;
        const float bv = srcSel ? bias[h0 + lm] : 0.0f;
        #pragma unroll
        for (int im = 0; im < 2; ++im)
            #pragma unroll
            for (int j = 0; j < 4; ++j)
                yt[mrow + im * 16 + quad * 4 + j][lm] = acc[im][j] + bv;
    }
    __syncthreads();

    // masked pair relu-sum: thread = (h in 0..15, i-chunk of 4)
    const int n1 = s1p[b];
    const int n2 = s2p[b];
    const int h  = t & 15;
    const int ic = t >> 4;   // 0..15

    float r1[4];
    #pragma unroll
    for (int ii = 0; ii < 4; ++ii) {
        const int i = ic * 4 + ii;
        r1[ii] = (i < n1) ? y1t[i][h] : -1e30f;  // invalid i -> relu gives 0
    }

    float ac[4] = {0.f, 0.f, 0.f, 0.f};
    int j = 0;
    for (; j + 4 <= n2; j += 4) {
        const float v0 = y2t[j][h];
        const float v1 = y2t[j + 1][h];
        const float v2 = y2t[j + 2][h];
        const float v3 = y2t[j + 3][h];
        #pragma unroll
        for (int ii = 0; ii < 4; ++ii) {
            ac[ii] += fmaxf(r1[ii] + v0, 0.f);
            ac[ii] += fmaxf(r1[ii] + v1, 0.f);
            ac[ii] += fmaxf(r1[ii] + v2, 0.f);
            ac[ii] += fmaxf(r1[ii] + v3, 0.f);
        }
    }
    for (; j < n2; ++j) {
        const float v0 = y2t[j][h];
        #pragma unroll
        for (int ii = 0; ii < 4; ++ii)
            ac[ii] += fmaxf(r1[ii] + v0, 0.f);
    }
    partial[ic][h] = (ac[0] + ac[1]) + (ac[2] + ac[3]);
    __syncthreads();

    if (t < HT) {
        float s = 0.f;
        #pragma unroll
        for (int ic2 = 0; ic2 < 16; ++ic2)
            s += partial[ic2][t];
        const float denom = (float)(n1 * n2);
        const float pad = (float)(LL * LL) - denom;
        out[b * HH + h0 + t] = (s + pad * fmaxf(bias[h0 + t], 0.f)) / denom;
    }
}

extern "C" void kernel_launch(void* const* d_in, const int* in_sizes, int n_in,
                              void* d_out, int out_size, void* d_ws, size_t ws_size,
                              hipStream_t stream) {
    const float* x1 = (const float*)d_in[0];
    const int*   s1 = (const int*)d_in[1];
    const float* x2 = (const float*)d_in[2];
    const int*   s2 = (const int*)d_in[3];
    const float* W  = (const float*)d_in[4];
    const float* b  = (const float*)d_in[5];
    float* out = (float*)d_out;
    (void)d_ws; (void)ws_size;

    fused_kernel<<<dim3(BB, HH / HT), 256, 0, stream>>>(x1, x2, W, s1, s2, b, out);
}